// Round 7
// baseline (126.603 us; speedup 1.0000x reference)
//
#include <hip/hip_runtime.h>
#include <hip/hip_bf16.h>

// MessagePassing: out[dst[e], :] += x[src[e], :] * w[e]
// x: [N, 64] f32, edge_index: [2, E] int32 (row0=src, row1=dst), w: [E,1] f32
// out: [N, 64] f32
//
// Round-16: K2-side levers were null 3x (MLP r10, locality r14, tail/occ
// r15) -> remaining fat is K1's payload scatter-write: with 1024+ bins per
// 4096-edge block, bin runs are 16-32B partial-line stores (~4096 lines/
// block) at the ~1.1-1.4 TB/s random-store rate r11 calibrated. Fix:
// coarse bins of 512 nodes (196 bins) -> runs ~21 edges ~168B, full-line
// near-stream writes; K1 LDS down to ~40KB. K2: each block = half a
// coarse bin (256 nodes), scans the bin's contiguous payload window twice
// (coalesced, L2-hot), filters its half, 256-key counting sort, then the
// unchanged 8-nodes-per-wave gather.

constexpr int D_FEAT        = 64;
constexpr int BIN_SHIFT     = 9;                  // 512 nodes / coarse bin
constexpr int NODES_PER_BIN = 1 << BIN_SHIFT;
constexpr int NBINS_MAX     = 256;                // supports n_nodes <= 131072
constexpr int BIN_CAP       = 8192;               // mean 6144 at E/N=12 -> +26 sigma
constexpr int EPB           = 4096;               // edges per partition block
constexpr int SED_CAP       = 4096;               // per-256-node-half cap (mean 3072)
constexpr int OVF_CAP       = 32768;

__device__ __forceinline__ int wave_incl_scan(int v, int lane) {
    #pragma unroll
    for (int d = 1; d < 64; d <<= 1) {
        int t = __shfl_up(v, d);
        if (lane >= d) v += t;
    }
    return v;
}

__device__ __forceinline__ unsigned short f32_to_bf16_rn(float f) {
    unsigned int u = __float_as_uint(f);
    u += 0x7FFFu + ((u >> 16) & 1u);
    return (unsigned short)(u >> 16);
}

// ---------------- K1: partition edges into 512-node bins + convert x->bf16 ----------------
__global__ __launch_bounds__(1024) void mp_partition(
    const int* __restrict__ src, const int* __restrict__ dst,
    const float* __restrict__ w, const float* __restrict__ x,
    ushort* __restrict__ xb, int n4,
    int*  __restrict__ gcnt,       // [nbins] global per-bin cursors (pre-zeroed)
    int2* __restrict__ payload,    // [nbins * BIN_CAP]
    int*  __restrict__ ovf_cnt, int4* __restrict__ ovf,
    int n_edges, int nbins)
{
    __shared__ int cnt[NBINS_MAX];                  // 1 KB
    __shared__ int start[NBINS_MAX];                // 1 KB
    __shared__ int cur[NBINS_MAX];                  // 1 KB
    __shared__ int gbase[NBINS_MAX];                // 1 KB
    __shared__ unsigned char binof[EPB];            // 4 KB
    __shared__ int2 sorted[EPB];                    // 32 KB

    const int t    = threadIdx.x;
    const int base = blockIdx.x * EPB;
    const int nblk = min(EPB, n_edges - base);

    // zero histogram first (no barrier needed until the atomics)
    if (t < NBINS_MAX) cnt[t] = 0;

    // issue the dst load NOW so its latency hides under the conversion loop
    const int i4 = (base >> 2) + t;
    const bool have = (i4 * 4 < n_edges);
    int4 d4 = make_int4(0, 0, 0, 0);
    if (have) d4 = reinterpret_cast<const int4*>(dst)[i4];

    // fused x -> bf16 conversion (grid-strided; independent of binning)
    for (int i = blockIdx.x * 1024 + t; i < n4; i += gridDim.x * 1024) {
        const float4 v = reinterpret_cast<const float4*>(x)[i];
        ushort4 o;
        o.x = f32_to_bf16_rn(v.x);
        o.y = f32_to_bf16_rn(v.y);
        o.z = f32_to_bf16_rn(v.z);
        o.w = f32_to_bf16_rn(v.w);
        reinterpret_cast<ushort4*>(xb)[i] = o;
    }
    __syncthreads();

    if (have) {
        atomicAdd(&cnt[d4.x >> BIN_SHIFT], 1);
        atomicAdd(&cnt[d4.y >> BIN_SHIFT], 1);
        atomicAdd(&cnt[d4.z >> BIN_SHIFT], 1);
        atomicAdd(&cnt[d4.w >> BIN_SHIFT], 1);
    }
    __syncthreads();

    // wave 0: 4-chunk carry scan over 256 bins; all threads: global base reservation
    if (t < 64) {
        int carry = 0;
        #pragma unroll
        for (int k = 0; k < 4; ++k) {
            const int idx = k * 64 + t;
            const int c = cnt[idx];
            const int s = wave_incl_scan(c, t) + carry;
            start[idx] = s - c;
            cur[idx]   = s - c;
            carry = __shfl(s, 63);
        }
    }
    for (int k = t; k < nbins; k += 1024) {
        const int c = cnt[k];
        if (c > 0) gbase[k] = atomicAdd(&gcnt[k], c);
    }
    __syncthreads();

    if (have) {
        const int4   s4 = reinterpret_cast<const int4*>(src)[i4];
        const float4 w4 = reinterpret_cast<const float4*>(w)[i4];
        const int   dd[4] = {d4.x, d4.y, d4.z, d4.w};
        const int   ss[4] = {s4.x, s4.y, s4.z, s4.w};
        const float ww[4] = {w4.x, w4.y, w4.z, w4.w};
        #pragma unroll
        for (int j = 0; j < 4; ++j) {
            const int b   = dd[j] >> BIN_SHIFT;
            const int low = dd[j] & (NODES_PER_BIN - 1);      // 9 bits
            const int p   = atomicAdd(&cur[b], 1);
            sorted[p] = make_int2((low << 20) | ss[j], __float_as_int(ww[j]));
            binof[p]  = (unsigned char)b;
        }
    }
    __syncthreads();

    // payload write: runs of ~21 consecutive edges per (bin, block) -> full lines
    #pragma unroll
    for (int k = 0; k < EPB / 1024; ++k) {
        const int i = k * 1024 + t;
        if (i >= nblk) break;
        const int b    = binof[i];
        const int idx  = i - start[b];
        const int gpos = gbase[b] + idx;
        const int2 e   = sorted[i];
        if (gpos < BIN_CAP) {
            payload[(size_t)b * BIN_CAP + gpos] = e;
        } else {
            const int op = atomicAdd(ovf_cnt, 1);
            if (op < OVF_CAP)
                ovf[op] = make_int4((b << BIN_SHIFT) + (e.x >> 20),
                                    e.x & 0xFFFFF, e.y, 0);
        }
    }
}

// ---------------- K2: half-bin (256 nodes) filter + sort + gather ----------------

#define ACC8(XV, WW) do {                                          \
    a0 = fmaf(__uint_as_float((XV).x << 16),         (WW), a0);    \
    a1 = fmaf(__uint_as_float((XV).x & 0xFFFF0000u), (WW), a1);    \
    a2 = fmaf(__uint_as_float((XV).y << 16),         (WW), a2);    \
    a3 = fmaf(__uint_as_float((XV).y & 0xFFFF0000u), (WW), a3);    \
    a4 = fmaf(__uint_as_float((XV).z << 16),         (WW), a4);    \
    a5 = fmaf(__uint_as_float((XV).z & 0xFFFF0000u), (WW), a5);    \
    a6 = fmaf(__uint_as_float((XV).w << 16),         (WW), a6);    \
    a7 = fmaf(__uint_as_float((XV).w & 0xFFFF0000u), (WW), a7);    \
} while (0)

__global__ __launch_bounds__(512) void mp_bin_gather(
    const ushort* __restrict__ xb,     // bf16 x rows (128 B)
    const float*  __restrict__ x,      // fp32 x (overflow path only)
    const int*  __restrict__ gcnt,
    const int2* __restrict__ payload,
    const int*  __restrict__ ovf_cnt, const int4* __restrict__ ovf,
    float* __restrict__ out, int n_nodes)
{
    __shared__ int2 sedge[SED_CAP];                 // 32 KB (node-sorted, my half)
    __shared__ int ncnt[256];
    __shared__ int nstart[257];
    __shared__ int ncur[256];

    const int bs   = blockIdx.x;
    const int b    = bs >> 1;            // coarse bin
    const int half = bs & 1;             // which 256-node half
    const int t    = threadIdx.x;
    const int wid  = t >> 6;             // 0..7
    const int lane = t & 63;
    const int sub  = lane >> 3;          // node slot within the wave batch
    const int fq   = lane & 7;           // feature octet
    const int fg   = fq * 8;

    const int m = min(gcnt[b], BIN_CAP);
    const int2* pl = payload + (size_t)b * BIN_CAP;

    if (t < 256) ncnt[t] = 0;
    __syncthreads();

    // pass 1: histogram my half's fine node ids (low bits 20..28; half = bit 28)
    for (int i = t; i < m; i += 512) {
        const int e = pl[i].x;
        if (((e >> 28) & 1) == half)
            atomicAdd(&ncnt[(e >> 20) & 255], 1);
    }
    __syncthreads();

    // wave 0: 4-chunk carry scan over 256 fine counters
    if (t < 64) {
        int carry = 0;
        #pragma unroll
        for (int k = 0; k < 4; ++k) {
            const int idx = k * 64 + t;
            const int c = ncnt[idx];
            const int s = wave_incl_scan(c, t) + carry;
            nstart[idx] = s - c;
            ncur[idx]   = s - c;
            carry = __shfl(s, 63);
        }
        if (t == 63) nstart[256] = carry;
    }
    __syncthreads();

    // pass 2: re-read window (L2-hot), scatter my half node-sorted into LDS
    for (int i = t; i < m; i += 512) {
        const int2 e = pl[i];
        if (((e.x >> 28) & 1) == half) {
            const int p = atomicAdd(&ncur[(e.x >> 20) & 255], 1);
            if (p < SED_CAP) sedge[p] = e;
        }
    }
    __syncthreads();

    const int novf = *ovf_cnt;  // usually 0

    #define XROW(SRC) (*reinterpret_cast<const uint4*>(xb + (size_t)(SRC) * D_FEAT + fg))

    // gather: 8 nodes per wave in parallel (8-lane group per node).
    // Wave wid owns fine nodes [wid*32, wid*32+32) as 4 batches of 8.
    #pragma unroll
    for (int nb = 0; nb < 32; nb += 8) {
        const int n    = wid * 32 + nb + sub;                 // fine node 0..255
        const int node = (b << BIN_SHIFT) + (half << 8) + n;
        const int s0 = nstart[n];
        const int s1 = nstart[n + 1];        // nodes >= n_nodes have s1==s0

        float a0 = 0.f, a1 = 0.f, a2 = 0.f, a3 = 0.f;
        float a4 = 0.f, a5 = 0.f, a6 = 0.f, a7 = 0.f;

        int e = s0;
        for (; e + 4 <= s1; e += 4) {        // 4 rows/group in flight
            const int2 pA = sedge[e];
            const int2 pB = sedge[e + 1];
            const int2 pC = sedge[e + 2];
            const int2 pD = sedge[e + 3];
            const uint4 xA = XROW(pA.x & 0xFFFFF);
            const uint4 xB = XROW(pB.x & 0xFFFFF);
            const uint4 xC = XROW(pC.x & 0xFFFFF);
            const uint4 xD = XROW(pD.x & 0xFFFFF);
            const float wA = __int_as_float(pA.y);
            const float wB = __int_as_float(pB.y);
            const float wC = __int_as_float(pC.y);
            const float wD = __int_as_float(pD.y);
            ACC8(xA, wA);
            ACC8(xB, wB);
            ACC8(xC, wC);
            ACC8(xD, wD);
        }
        if (e + 2 <= s1) {
            const int2 pA = sedge[e];
            const int2 pB = sedge[e + 1];
            const uint4 xA = XROW(pA.x & 0xFFFFF);
            const uint4 xB = XROW(pB.x & 0xFFFFF);
            const float wA = __int_as_float(pA.y);
            const float wB = __int_as_float(pB.y);
            ACC8(xA, wA);
            ACC8(xB, wB);
            e += 2;
        }
        if (e < s1) {
            const int2 p = sedge[e];
            const uint4 xv = XROW(p.x & 0xFFFFF);
            const float ww = __int_as_float(p.y);
            ACC8(xv, ww);
        }

        if (node < n_nodes) {
            if (novf > 0) {  // rare overflow path (fp32 x)
                const int lim = min(novf, OVF_CAP);
                for (int j = 0; j < lim; ++j) {
                    const int4 o = ovf[j];
                    if (o.x == node) {
                        const float* xr = x + (size_t)o.y * D_FEAT + fg;
                        const float ww = __int_as_float(o.z);
                        a0 = fmaf(xr[0], ww, a0); a1 = fmaf(xr[1], ww, a1);
                        a2 = fmaf(xr[2], ww, a2); a3 = fmaf(xr[3], ww, a3);
                        a4 = fmaf(xr[4], ww, a4); a5 = fmaf(xr[5], ww, a5);
                        a6 = fmaf(xr[6], ww, a6); a7 = fmaf(xr[7], ww, a7);
                    }
                }
            }
            float* orow = out + (size_t)node * D_FEAT + fg;
            *reinterpret_cast<float4*>(orow)     = make_float4(a0, a1, a2, a3);
            *reinterpret_cast<float4*>(orow + 4) = make_float4(a4, a5, a6, a7);
        }
    }
    #undef XROW
}

// ---------------- fallback: atomic scatter (round-1, known correct) ----------------
__global__ __launch_bounds__(256) void mp_scatter_atomic(
    const float* __restrict__ x, const int* __restrict__ src,
    const int* __restrict__ dst, const float* __restrict__ w,
    float* __restrict__ out, int n_edges)
{
    const int gtid = blockIdx.x * blockDim.x + threadIdx.x;
    const int edge = gtid >> 6;
    const int lane = threadIdx.x & 63;
    if (edge >= n_edges) return;
    const int s = src[edge];
    const int d = dst[edge];
    const float ww = w[edge];
    atomicAdd(&out[(size_t)d * D_FEAT + lane], x[(size_t)s * D_FEAT + lane] * ww);
}

extern "C" void kernel_launch(void* const* d_in, const int* in_sizes, int n_in,
                              void* d_out, int out_size, void* d_ws, size_t ws_size,
                              hipStream_t stream)
{
    const float* x          = (const float*)d_in[0];
    const int*   edge_index = (const int*)d_in[1];   // [2, E]
    const float* w          = (const float*)d_in[2]; // [E, 1]
    float*       out        = (float*)d_out;

    const int n_edges = in_sizes[1] / 2;
    const int n_nodes = in_sizes[0] / D_FEAT;
    const int* src = edge_index;
    const int* dst = edge_index + n_edges;

    const int nbins = (n_nodes + NODES_PER_BIN - 1) >> BIN_SHIFT;

    // ws layout: gcnt[NBINS_MAX] | ovf_cnt(+pad 64 ints) | ovf[OVF_CAP] int4
    //          | payload[nbins*BIN_CAP] int2 | xb[n_nodes*64] bf16
    int*    gcnt    = (int*)d_ws;
    int*    ovf_cnt = gcnt + NBINS_MAX;
    int4*   ovf     = (int4*)(gcnt + NBINS_MAX + 64);
    int2*   payload = (int2*)(ovf + OVF_CAP);
    ushort* xb      = (ushort*)(payload + (size_t)nbins * BIN_CAP);
    const size_t need = (size_t)(NBINS_MAX + 64) * 4 + (size_t)OVF_CAP * 16
                      + (size_t)nbins * BIN_CAP * 8
                      + (size_t)n_nodes * D_FEAT * 2;

    const bool ok = (ws_size >= need) && (nbins <= NBINS_MAX) && ((n_edges & 3) == 0)
                 && ((n_nodes * D_FEAT) % 4 == 0) && (n_nodes <= 131072);

    if (ok) {
        hipMemsetAsync(gcnt, 0, (size_t)(NBINS_MAX + 64) * 4, stream);
        const int n4 = n_nodes * D_FEAT / 4;
        const int g1 = (n_edges + EPB - 1) / EPB;
        mp_partition<<<g1, 1024, 0, stream>>>(src, dst, w, x, xb, n4,
                                              gcnt, payload, ovf_cnt, ovf,
                                              n_edges, nbins);
        mp_bin_gather<<<nbins * 2, 512, 0, stream>>>(xb, x, gcnt, payload,
                                                     ovf_cnt, ovf, out, n_nodes);
        return;
    }

    // fallback: atomic scatter
    hipMemsetAsync(d_out, 0, (size_t)out_size * sizeof(float), stream);
    const int grid = (int)(((size_t)n_edges * 64 + 255) / 256);
    mp_scatter_atomic<<<grid, 256, 0, stream>>>(x, src, dst, w, out, n_edges);
}